// Round 1
// baseline (613.187 us; speedup 1.0000x reference)
//
#include <hip/hip_runtime.h>

// MoE grouped GEMM: Y[T, OUT] = X[T, IN] @ W[e, OUT, IN]^T + bias[e, OUT]
//
// Round 4: depth-3 software-pipelined bf16 GEMM (T3/T4-style counted vmcnt):
//   - BM=256 x BN=128 x BK=32, 512 threads (8 waves), wave = 64x64 out tile
//   - 4 LDS slots (24 KB each, 96 KB total); stage tile kt+3 while computing kt
//   - s_waitcnt vmcnt(6) + raw s_barrier per K-tile: loads stay in flight
//     across barriers (never drain vmcnt in the main loop)
//   - T2 XOR swizzle (granule ^= (row>>1)&3): inverse-swizzled global source +
//     swizzled ds_read, linear LDS dest (global_load_lds-compatible)
//   - partial expert tiles: clamp A source rows (uniform load count per wave,
//     keeps vmcnt arithmetic exact); garbage rows never stored
//   - s_setprio(1) around the MFMA cluster (T5)
// Pre-convert X and W to bf16 in d_ws (unchanged); f32 fallback kept.

typedef __attribute__((ext_vector_type(8))) short s16x8;   // 8 bf16
typedef __attribute__((ext_vector_type(4))) short s16x4;   // 4 bf16
typedef __attribute__((ext_vector_type(4))) float f32x4;

typedef __attribute__((address_space(1))) void gv_t;       // global
typedef __attribute__((address_space(3))) void lv_t;       // LDS

// pipelined kernel geometry
#define PBM 256
#define PBN 128
#define PBK 32
#define PTHREADS 512
#define ASLOT (PBM * PBK)   // shorts per A slot (16 KB)
#define BSLOT (PBN * PBK)   // shorts per B slot (8 KB)

// fallback kernel geometry
#define FBM 128
#define FBN 128
#define FBK 32
#define LDK 40

__device__ __forceinline__ short f2bf(float f) {
    union { float f; unsigned u; } v; v.f = f;
    unsigned r = v.u + 0x7FFFu + ((v.u >> 16) & 1u);
    return (short)(r >> 16);
}

__device__ __forceinline__ long long load_off(const void* p, int i, bool i64) {
    if (i64) return ((const long long*)p)[i];
    return (long long)((const int*)p)[i];
}

// ---- fp32 -> bf16 elementwise convert (float4 in, short4 out) ----
__global__ __launch_bounds__(256)
void cvt_kernel(const float* __restrict__ src, short* __restrict__ dst, int n4) {
    int i = blockIdx.x * 256 + threadIdx.x;
    if (i >= n4) return;
    float4 v = ((const float4*)src)[i];
    s16x4 b;
    b.x = f2bf(v.x); b.y = f2bf(v.y); b.z = f2bf(v.z); b.w = f2bf(v.w);
    ((s16x4*)dst)[i] = b;
}

// ---- map blockIdx.y slot -> (expert, row0, rows) for tile height bm ----
__device__ __forceinline__ bool sched_tile(const void* offp, bool off_i64, int NEXP,
                                           int slot, int bm,
                                           int& e_out, long long& row0, int& rows) {
    int acc_t = 0;
    for (int e = 0; e < NEXP; ++e) {
        long long s = load_off(offp, e, off_i64);
        long long t = load_off(offp, e + 1, off_i64);
        int n = (int)(t - s);
        int nt = (n + bm - 1) / bm;
        if (slot < acc_t + nt) {
            int lt = slot - acc_t;
            row0 = s + (long long)lt * bm;
            rows = (int)(t - row0);
            if (rows > bm) rows = bm;
            e_out = e;
            return true;
        }
        acc_t += nt;
    }
    return false;
}

// ---- main GEMM: bf16 inputs, depth-3 pipelined staging, counted vmcnt ----
__global__ __launch_bounds__(PTHREADS, 2)
void moe_gemm_bf16_pipe(const short* __restrict__ Xb16,
                        const void* __restrict__ offp,
                        const short* __restrict__ Wb16,
                        const float* __restrict__ Bias,
                        float* __restrict__ Y,
                        int IN_F, int OUT_F, int NEXP, int Ttot) {
    const bool off_i64 = (((const int*)offp)[NEXP] != Ttot);

    int e_found; long long row0; int rows;
    if (!sched_tile(offp, off_i64, NEXP, blockIdx.y, PBM, e_found, row0, rows)) return;

    const int n0 = blockIdx.x * PBN;
    const int tid = threadIdx.x;
    const int wave = tid >> 6;           // 0..7
    const int lane = tid & 63;
    const int wm = (wave >> 1) * 64;     // 0,64,128,192
    const int wn = (wave & 1) * 64;      // 0,64
    const int lrow = lane & 15;
    const int kg = lane >> 4;            // 0..3
    const int sw = (lrow >> 1) & 3;      // read-side swizzle bits

    // 4 double... quad-buffered slots; linear row-major [row][32] per slot.
    // Content contract: physical granule (row, g) holds logical granule
    // g ^ ((row>>1)&3) of that row (XOR involution; both sides use it).
    __shared__ __align__(16) short As[4 * ASLOT];   // 64 KB
    __shared__ __align__(16) short Bs[4 * BSLOT];   // 32 KB

    const short* Xb = Xb16 + (size_t)row0 * IN_F;
    const short* Wb = Wb16 + (size_t)e_found * OUT_F * IN_F + (size_t)n0 * IN_F;

    // staging geometry: each wave-instruction writes 1024 B = 16 rows of 64 B,
    // lane l -> LDS bytes base + l*16 -> (row = l>>2, granule = l&3).
    const int lr4 = lane >> 2;                            // row within 16-row group
    const int colOff = ((lane & 3) ^ ((lr4 >> 1) & 3)) * 8;  // inverse-swizzled src col
    const int ra0 = wave * 16 + lr4;                      // A rows 0..127   (round 0)
    const int ra1 = 128 + wave * 16 + lr4;                // A rows 128..255 (round 1)
    const int ra0c = ra0 < rows ? ra0 : rows - 1;         // clamp: uniform load count
    const int ra1c = ra1 < rows ? ra1 : rows - 1;
    const int rb = wave * 16 + lr4;                       // B rows 0..127

    const short* srcA0 = Xb + (size_t)ra0c * IN_F + colOff;
    const short* srcA1 = Xb + (size_t)ra1c * IN_F + colOff;
    const short* srcB  = Wb + (size_t)rb * IN_F + colOff;
    const int dA0 = wave * 512;            // shorts; wave-uniform LDS base
    const int dA1 = (8 + wave) * 512;
    const int dB  = wave * 512;

    const int nkt = IN_F / PBK;

    auto STAGE = [&](int kt_) {
        const int s_ = kt_ & 3;
        const int ko_ = kt_ * PBK;
        __builtin_amdgcn_global_load_lds((gv_t*)(srcA0 + ko_),
                                         (lv_t*)(As + s_ * ASLOT + dA0), 16, 0, 0);
        __builtin_amdgcn_global_load_lds((gv_t*)(srcA1 + ko_),
                                         (lv_t*)(As + s_ * ASLOT + dA1), 16, 0, 0);
        __builtin_amdgcn_global_load_lds((gv_t*)(srcB + ko_),
                                         (lv_t*)(Bs + s_ * BSLOT + dB), 16, 0, 0);
    };

    STAGE(0);
    if (nkt > 1) STAGE(1);
    if (nkt > 2) STAGE(2);

    f32x4 acc[4][4] = {};

    for (int kt = 0; kt < nkt; ++kt) {
        // wait for tile kt's own 3 loads; keep tiles kt+1, kt+2 in flight
        if (kt + 2 < nkt)      asm volatile("s_waitcnt vmcnt(6)" ::: "memory");
        else if (kt + 1 < nkt) asm volatile("s_waitcnt vmcnt(3)" ::: "memory");
        else                   asm volatile("s_waitcnt vmcnt(0)" ::: "memory");
        // barrier: (a) tile kt resident for all waves,
        //          (b) all waves done reading slot (kt-1)&3 = (kt+3)&3
        asm volatile("s_barrier" ::: "memory");

        if (kt + 3 < nkt) STAGE(kt + 3);   // into the slot freed at this barrier

        const short* aS = As + (kt & 3) * ASLOT;
        const short* bS = Bs + (kt & 3) * BSLOT;
        s16x8 af[4], bf[4];
        #pragma unroll
        for (int i = 0; i < 4; ++i)
            af[i] = *(const s16x8*)&aS[(wm + i * 16 + lrow) * PBK + ((kg ^ sw) * 8)];
        #pragma unroll
        for (int j = 0; j < 4; ++j)
            bf[j] = *(const s16x8*)&bS[(wn + j * 16 + lrow) * PBK + ((kg ^ sw) * 8)];

        __builtin_amdgcn_s_setprio(1);
        #pragma unroll
        for (int i = 0; i < 4; ++i)
            #pragma unroll
            for (int j = 0; j < 4; ++j)
                acc[i][j] = __builtin_amdgcn_mfma_f32_16x16x32_bf16(
                    af[i], bf[j], acc[i][j], 0, 0, 0);
        __builtin_amdgcn_s_setprio(0);
    }

    // epilogue: C/D map col = lane&15, row = (lane>>4)*4 + reg
    float bv[4];
    #pragma unroll
    for (int j = 0; j < 4; ++j)
        bv[j] = Bias[(size_t)e_found * OUT_F + n0 + wn + j * 16 + lrow];

    #pragma unroll
    for (int i = 0; i < 4; ++i) {
        #pragma unroll
        for (int r = 0; r < 4; ++r) {
            int rr = wm + i * 16 + kg * 4 + r;
            if (rr < rows) {
                float* yrow = Y + (size_t)(row0 + rr) * OUT_F + n0;
                #pragma unroll
                for (int j = 0; j < 4; ++j)
                    yrow[wn + j * 16 + lrow] = acc[i][j][r] + bv[j];
            }
        }
    }
}

// ---- fallback: fp32 inputs, in-kernel cvt (round-2 kernel, verified) ----
__global__ __launch_bounds__(256, 2)
void moe_gemm_f32(const float* __restrict__ X,
                  const void* __restrict__ offp,
                  const float* __restrict__ W,
                  const float* __restrict__ Bias,
                  float* __restrict__ Y,
                  int IN_F, int OUT_F, int NEXP, int Ttot) {
    const bool off_i64 = (((const int*)offp)[NEXP] != Ttot);
    int e_found; long long row0; int rows;
    if (!sched_tile(offp, off_i64, NEXP, blockIdx.y, FBM, e_found, row0, rows)) return;

    const int n0 = blockIdx.x * FBN;
    const int tid = threadIdx.x;
    const int wave = tid >> 6;
    const int lane = tid & 63;
    const int wm = (wave & 1) * 64;
    const int wn = (wave >> 1) * 64;
    const int lrow = lane & 15;
    const int kg = lane >> 4;

    __shared__ __align__(16) short As[FBM][LDK];
    __shared__ __align__(16) short Bs[FBN][LDK];

    const float* Xb = X + (size_t)row0 * IN_F;
    const float* Wb = W + (size_t)e_found * OUT_F * IN_F + (size_t)n0 * IN_F;

    f32x4 acc[4][4] = {};

    for (int k0 = 0; k0 < IN_F; k0 += FBK) {
        __syncthreads();
        #pragma unroll
        for (int p = 0; p < 4; ++p) {
            int idx = p * 256 + tid;
            int r = idx >> 3;
            int kc = (idx & 7) << 2;
            float4 v = make_float4(0.f, 0.f, 0.f, 0.f);
            if (r < rows) v = *(const float4*)(Xb + (size_t)r * IN_F + k0 + kc);
            s16x4 b;
            b.x = f2bf(v.x); b.y = f2bf(v.y); b.z = f2bf(v.z); b.w = f2bf(v.w);
            *(s16x4*)&As[r][kc] = b;
        }
        #pragma unroll
        for (int p = 0; p < 4; ++p) {
            int idx = p * 256 + tid;
            int r = idx >> 3;
            int kc = (idx & 7) << 2;
            float4 v = *(const float4*)(Wb + (size_t)r * IN_F + k0 + kc);
            s16x4 b;
            b.x = f2bf(v.x); b.y = f2bf(v.y); b.z = f2bf(v.z); b.w = f2bf(v.w);
            *(s16x4*)&Bs[r][kc] = b;
        }
        __syncthreads();

        s16x8 af[4], bf[4];
        #pragma unroll
        for (int i = 0; i < 4; ++i)
            af[i] = *(const s16x8*)&As[wm + i * 16 + lrow][kg * 8];
        #pragma unroll
        for (int j = 0; j < 4; ++j)
            bf[j] = *(const s16x8*)&Bs[wn + j * 16 + lrow][kg * 8];

        #pragma unroll
        for (int i = 0; i < 4; ++i)
            #pragma unroll
            for (int j = 0; j < 4; ++j)
                acc[i][j] = __builtin_amdgcn_mfma_f32_16x16x32_bf16(
                    af[i], bf[j], acc[i][j], 0, 0, 0);
    }

    float bv[4];
    #pragma unroll
    for (int j = 0; j < 4; ++j)
        bv[j] = Bias[(size_t)e_found * OUT_F + n0 + wn + j * 16 + lrow];

    #pragma unroll
    for (int i = 0; i < 4; ++i) {
        #pragma unroll
        for (int r = 0; r < 4; ++r) {
            int rr = wm + i * 16 + kg * 4 + r;
            if (rr < rows) {
                float* yrow = Y + (size_t)(row0 + rr) * OUT_F + n0;
                #pragma unroll
                for (int j = 0; j < 4; ++j)
                    yrow[wn + j * 16 + lrow] = acc[i][j][r] + bv[j];
            }
        }
    }
}

extern "C" void kernel_launch(void* const* d_in, const int* in_sizes, int n_in,
                              void* d_out, int out_size, void* d_ws, size_t ws_size,
                              hipStream_t stream) {
    const float* X = (const float*)d_in[0];
    const void* off = d_in[1];
    const float* W = (const float*)d_in[2];
    const float* Bias = (const float*)d_in[3];
    float* Y = (float*)d_out;

    const int NEXP1 = in_sizes[1];
    const int NEXP = NEXP1 - 1;
    const int OUT_F = in_sizes[3] / NEXP;
    const int IN_F = (int)((long long)in_sizes[2] / NEXP / OUT_F);
    const int T = in_sizes[0] / IN_F;

    const long long Xn = (long long)T * IN_F;                    // elements
    const long long Wn = (long long)NEXP * OUT_F * IN_F;
    const size_t need = (size_t)(Xn + Wn) * sizeof(short);

    const bool shape_ok = (OUT_F % PBN == 0) && (IN_F % PBK == 0) &&
                          (Xn % 4 == 0) && (Wn % 4 == 0);

    if (shape_ok && ws_size >= need) {
        short* wsX = (short*)d_ws;
        short* wsW = wsX + Xn;
        {
            int n4 = (int)(Xn / 4);
            cvt_kernel<<<(n4 + 255) / 256, 256, 0, stream>>>(X, wsX, n4);
        }
        {
            int n4 = (int)(Wn / 4);
            cvt_kernel<<<(n4 + 255) / 256, 256, 0, stream>>>(W, wsW, n4);
        }
        const int maxRowTiles = T / PBM + NEXP;
        dim3 grid(OUT_F / PBN, maxRowTiles);
        moe_gemm_bf16_pipe<<<grid, PTHREADS, 0, stream>>>(wsX, off, wsW, Bias, Y,
                                                          IN_F, OUT_F, NEXP, T);
    } else {
        const int maxRowTiles = T / FBM + NEXP;
        dim3 grid(OUT_F / FBN, maxRowTiles);
        moe_gemm_f32<<<grid, 256, 0, stream>>>(X, off, W, Bias, Y,
                                               IN_F, OUT_F, NEXP, T);
    }
}

// Round 2
// 572.735 us; speedup vs baseline: 1.0706x; 1.0706x over previous
//
#include <hip/hip_runtime.h>

// MoE grouped GEMM: Y[T, OUT] = X[T, IN] @ W[e, OUT, IN]^T + bias[e, OUT]
//
// Round 5: attack the staging-bandwidth wall found in round 4 (MfmaUtil 18.6%,
// staging rate 5.2 TB/s at intensity 85 flop/B => 460 TF cap):
//   - 256x256 tile (BK=32): intensity 128 flop/B (+50% FLOPs per staged byte)
//   - grid.x = OUT_F/256 = 8 = NXCD: blkid%8 == N-block, so each XCD keeps one
//     1 MB W-panel L2-resident => B staging served by L2 instead of L3
//   - same verified sync skeleton as round 4: 4 LDS slots (128 KB), depth-3
//     prefetch, ONE raw s_barrier per K-tile, counted vmcnt (8/4/0), clamped
//     A rows for partial expert tiles (uniform per-wave vmcnt counts)
//   - finer interleave: stage loads spread between ds_read/MFMA clusters
//   - cvt kernels: grid-stride, <=4096 blocks (round-4 launched 32768 tiny
//     workgroups per cvt => ~280 us of dispatch ramp)

typedef __attribute__((ext_vector_type(8))) short s16x8;   // 8 bf16
typedef __attribute__((ext_vector_type(4))) short s16x4;   // 4 bf16
typedef __attribute__((ext_vector_type(4))) float f32x4;

typedef __attribute__((address_space(1))) void gv_t;       // global
typedef __attribute__((address_space(3))) void lv_t;       // LDS

// main kernel geometry
#define QBM 256
#define QBN 256
#define QBK 32
#define QTHREADS 512
#define QASLOT (QBM * QBK)   // shorts per A slot (16 KB)
#define QBSLOT (QBN * QBK)   // shorts per B slot (16 KB)

// fallback kernel geometry
#define FBM 128
#define FBN 128
#define FBK 32
#define LDK 40

__device__ __forceinline__ short f2bf(float f) {
    union { float f; unsigned u; } v; v.f = f;
    unsigned r = v.u + 0x7FFFu + ((v.u >> 16) & 1u);
    return (short)(r >> 16);
}

__device__ __forceinline__ long long load_off(const void* p, int i, bool i64) {
    if (i64) return ((const long long*)p)[i];
    return (long long)((const int*)p)[i];
}

// ---- fp32 -> bf16 elementwise convert (grid-stride, float4 in, short4 out) ----
__global__ __launch_bounds__(256)
void cvt_kernel(const float* __restrict__ src, short* __restrict__ dst, long long n4) {
    long long stride = (long long)gridDim.x * 256;
    for (long long i = (long long)blockIdx.x * 256 + threadIdx.x; i < n4; i += stride) {
        float4 v = ((const float4*)src)[i];
        s16x4 b;
        b.x = f2bf(v.x); b.y = f2bf(v.y); b.z = f2bf(v.z); b.w = f2bf(v.w);
        ((s16x4*)dst)[i] = b;
    }
}

// ---- map blockIdx.y slot -> (expert, row0, rows) for tile height bm ----
__device__ __forceinline__ bool sched_tile(const void* offp, bool off_i64, int NEXP,
                                           int slot, int bm,
                                           int& e_out, long long& row0, int& rows) {
    int acc_t = 0;
    for (int e = 0; e < NEXP; ++e) {
        long long s = load_off(offp, e, off_i64);
        long long t = load_off(offp, e + 1, off_i64);
        int n = (int)(t - s);
        int nt = (n + bm - 1) / bm;
        if (slot < acc_t + nt) {
            int lt = slot - acc_t;
            row0 = s + (long long)lt * bm;
            rows = (int)(t - row0);
            if (rows > bm) rows = bm;
            e_out = e;
            return true;
        }
        acc_t += nt;
    }
    return false;
}

// ---- main GEMM: 256x256 tile, depth-3 pipelined staging, counted vmcnt ----
__global__ __launch_bounds__(QTHREADS, 2)
void moe_gemm_bf16_256(const short* __restrict__ Xb16,
                       const void* __restrict__ offp,
                       const short* __restrict__ Wb16,
                       const float* __restrict__ Bias,
                       float* __restrict__ Y,
                       int IN_F, int OUT_F, int NEXP, int Ttot) {
    const bool off_i64 = (((const int*)offp)[NEXP] != Ttot);

    int e_found; long long row0; int rows;
    if (!sched_tile(offp, off_i64, NEXP, blockIdx.y, QBM, e_found, row0, rows)) return;

    const int n0 = blockIdx.x * QBN;
    const int tid = threadIdx.x;
    const int wave = tid >> 6;           // 0..7
    const int lane = tid & 63;
    const int wm = (wave >> 2) * 128;    // 0,128   (2 M sub-tiles)
    const int wn = (wave & 3) * 64;      // 0,64,128,192 (4 N sub-tiles)
    const int lrow = lane & 15;
    const int kg = lane >> 4;            // 0..3
    const int swr = (lrow >> 1) & 3;     // read-side swizzle key

    // 4 K-tile slots, linear row-major [row][32] (64 B rows).
    // Swizzle contract: physical granule (row, g) holds logical granule
    // g ^ ((row>>1)&3); write side permutes the GLOBAL source column,
    // read side XORs the granule index. (Round-4: 0 bank conflicts.)
    __shared__ __align__(16) short As[4 * QASLOT];   // 64 KB
    __shared__ __align__(16) short Bs[4 * QBSLOT];   // 64 KB

    const short* Xb = Xb16 + (size_t)row0 * IN_F;
    const short* Wb = Wb16 + (size_t)e_found * OUT_F * IN_F + (size_t)n0 * IN_F;

    // staging: one global_load_lds = 1024 B = 32 rows x 32 B? no: 16 B/lane,
    // 64 lanes -> 1 KB -> 16 rows of 64 B: lane l -> row l>>2, granule l&3.
    const int lr4 = lane >> 2;                               // row-local 0..15
    const int colOff = ((lane & 3) ^ ((lr4 >> 1) & 3)) * 8;  // inverse-swz src col (shorts)
    const int ra0 = wave * 16 + lr4;                         // A rows 0..127
    const int ra1 = 128 + wave * 16 + lr4;                   // A rows 128..255
    const int ra0c = ra0 < rows ? ra0 : rows - 1;            // clamp: uniform vmcnt
    const int ra1c = ra1 < rows ? ra1 : rows - 1;
    const int rb = wave * 16 + lr4;                          // B row base (q adds 128)

    const short* srcA0 = Xb + (size_t)ra0c * IN_F + colOff;
    const short* srcA1 = Xb + (size_t)ra1c * IN_F + colOff;
    const short* srcB0 = Wb + (size_t)rb * IN_F + colOff;
    const short* srcB1 = Wb + (size_t)(128 + rb) * IN_F + colOff;
    const int dA0 = wave * 512;              // shorts; wave-uniform LDS bases
    const int dA1 = 4096 + wave * 512;
    const int dB0 = wave * 512;
    const int dB1 = 4096 + wave * 512;

    const int nkt = IN_F / QBK;

    auto ST_A0 = [&](int kt_) {
        __builtin_amdgcn_global_load_lds((gv_t*)(srcA0 + (size_t)kt_ * QBK),
                                         (lv_t*)(As + (kt_ & 3) * QASLOT + dA0), 16, 0, 0);
    };
    auto ST_A1 = [&](int kt_) {
        __builtin_amdgcn_global_load_lds((gv_t*)(srcA1 + (size_t)kt_ * QBK),
                                         (lv_t*)(As + (kt_ & 3) * QASLOT + dA1), 16, 0, 0);
    };
    auto ST_B0 = [&](int kt_) {
        __builtin_amdgcn_global_load_lds((gv_t*)(srcB0 + (size_t)kt_ * QBK),
                                         (lv_t*)(Bs + (kt_ & 3) * QBSLOT + dB0), 16, 0, 0);
    };
    auto ST_B1 = [&](int kt_) {
        __builtin_amdgcn_global_load_lds((gv_t*)(srcB1 + (size_t)kt_ * QBK),
                                         (lv_t*)(Bs + (kt_ & 3) * QBSLOT + dB1), 16, 0, 0);
    };

    // prologue: stage tiles 0,1,2 (4 loads each)
    ST_A0(0); ST_A1(0); ST_B0(0); ST_B1(0);
    if (nkt > 1) { ST_A0(1); ST_A1(1); ST_B0(1); ST_B1(1); }
    if (nkt > 2) { ST_A0(2); ST_A1(2); ST_B0(2); ST_B1(2); }

    f32x4 acc[8][4] = {};

    for (int kt = 0; kt < nkt; ++kt) {
        // wait for tile kt's own 4 loads; keep tiles kt+1, kt+2 in flight
        if (kt + 2 < nkt)      asm volatile("s_waitcnt vmcnt(8)" ::: "memory");
        else if (kt + 1 < nkt) asm volatile("s_waitcnt vmcnt(4)" ::: "memory");
        else                   asm volatile("s_waitcnt vmcnt(0)" ::: "memory");
        // barrier: (a) tile kt resident for all waves,
        //          (b) all waves done reading slot (kt+3)&3 = (kt-1)&3
        asm volatile("s_barrier" ::: "memory");

        const bool pf = (kt + 3 < nkt);
        const int kp = kt + 3;
        const short* aS = As + (kt & 3) * QASLOT;
        const short* bS = Bs + (kt & 3) * QBSLOT;

        // B fragments (shared across all 8 m-frags) + staggered staging
        s16x8 bfr[4];
        #pragma unroll
        for (int j = 0; j < 4; ++j)
            bfr[j] = *(const s16x8*)&bS[(wn + j * 16 + lrow) * QBK + ((kg ^ swr) * 8)];
        if (pf) ST_A0(kp);

        s16x8 af0 = *(const s16x8*)&aS[(wm + 0 * 16 + lrow) * QBK + ((kg ^ swr) * 8)];
        s16x8 af1 = *(const s16x8*)&aS[(wm + 1 * 16 + lrow) * QBK + ((kg ^ swr) * 8)];
        if (pf) ST_A1(kp);
        __builtin_amdgcn_s_setprio(1);
        #pragma unroll
        for (int j = 0; j < 4; ++j) {
            acc[0][j] = __builtin_amdgcn_mfma_f32_16x16x32_bf16(af0, bfr[j], acc[0][j], 0, 0, 0);
            acc[1][j] = __builtin_amdgcn_mfma_f32_16x16x32_bf16(af1, bfr[j], acc[1][j], 0, 0, 0);
        }
        __builtin_amdgcn_s_setprio(0);

        s16x8 af2 = *(const s16x8*)&aS[(wm + 2 * 16 + lrow) * QBK + ((kg ^ swr) * 8)];
        s16x8 af3 = *(const s16x8*)&aS[(wm + 3 * 16 + lrow) * QBK + ((kg ^ swr) * 8)];
        if (pf) ST_B0(kp);
        __builtin_amdgcn_s_setprio(1);
        #pragma unroll
        for (int j = 0; j < 4; ++j) {
            acc[2][j] = __builtin_amdgcn_mfma_f32_16x16x32_bf16(af2, bfr[j], acc[2][j], 0, 0, 0);
            acc[3][j] = __builtin_amdgcn_mfma_f32_16x16x32_bf16(af3, bfr[j], acc[3][j], 0, 0, 0);
        }
        __builtin_amdgcn_s_setprio(0);

        s16x8 af4 = *(const s16x8*)&aS[(wm + 4 * 16 + lrow) * QBK + ((kg ^ swr) * 8)];
        s16x8 af5 = *(const s16x8*)&aS[(wm + 5 * 16 + lrow) * QBK + ((kg ^ swr) * 8)];
        if (pf) ST_B1(kp);
        __builtin_amdgcn_s_setprio(1);
        #pragma unroll
        for (int j = 0; j < 4; ++j) {
            acc[4][j] = __builtin_amdgcn_mfma_f32_16x16x32_bf16(af4, bfr[j], acc[4][j], 0, 0, 0);
            acc[5][j] = __builtin_amdgcn_mfma_f32_16x16x32_bf16(af5, bfr[j], acc[5][j], 0, 0, 0);
        }
        __builtin_amdgcn_s_setprio(0);

        s16x8 af6 = *(const s16x8*)&aS[(wm + 6 * 16 + lrow) * QBK + ((kg ^ swr) * 8)];
        s16x8 af7 = *(const s16x8*)&aS[(wm + 7 * 16 + lrow) * QBK + ((kg ^ swr) * 8)];
        __builtin_amdgcn_s_setprio(1);
        #pragma unroll
        for (int j = 0; j < 4; ++j) {
            acc[6][j] = __builtin_amdgcn_mfma_f32_16x16x32_bf16(af6, bfr[j], acc[6][j], 0, 0, 0);
            acc[7][j] = __builtin_amdgcn_mfma_f32_16x16x32_bf16(af7, bfr[j], acc[7][j], 0, 0, 0);
        }
        __builtin_amdgcn_s_setprio(0);
    }

    // epilogue: C/D map col = lane&15, row = (lane>>4)*4 + reg
    float bv[4];
    #pragma unroll
    for (int j = 0; j < 4; ++j)
        bv[j] = Bias[(size_t)e_found * OUT_F + n0 + wn + j * 16 + lrow];

    #pragma unroll
    for (int i = 0; i < 8; ++i) {
        #pragma unroll
        for (int r = 0; r < 4; ++r) {
            int rr = wm + i * 16 + kg * 4 + r;
            if (rr < rows) {
                float* yrow = Y + (size_t)(row0 + rr) * OUT_F + n0;
                #pragma unroll
                for (int j = 0; j < 4; ++j)
                    yrow[wn + j * 16 + lrow] = acc[i][j][r] + bv[j];
            }
        }
    }
}

// ---- fallback: fp32 inputs, in-kernel cvt (round-2 kernel, verified) ----
__global__ __launch_bounds__(256, 2)
void moe_gemm_f32(const float* __restrict__ X,
                  const void* __restrict__ offp,
                  const float* __restrict__ W,
                  const float* __restrict__ Bias,
                  float* __restrict__ Y,
                  int IN_F, int OUT_F, int NEXP, int Ttot) {
    const bool off_i64 = (((const int*)offp)[NEXP] != Ttot);
    int e_found; long long row0; int rows;
    if (!sched_tile(offp, off_i64, NEXP, blockIdx.y, FBM, e_found, row0, rows)) return;

    const int n0 = blockIdx.x * FBN;
    const int tid = threadIdx.x;
    const int wave = tid >> 6;
    const int lane = tid & 63;
    const int wm = (wave & 1) * 64;
    const int wn = (wave >> 1) * 64;
    const int lrow = lane & 15;
    const int kg = lane >> 4;

    __shared__ __align__(16) short As[FBM][LDK];
    __shared__ __align__(16) short Bs[FBN][LDK];

    const float* Xb = X + (size_t)row0 * IN_F;
    const float* Wb = W + (size_t)e_found * OUT_F * IN_F + (size_t)n0 * IN_F;

    f32x4 acc[4][4] = {};

    for (int k0 = 0; k0 < IN_F; k0 += FBK) {
        __syncthreads();
        #pragma unroll
        for (int p = 0; p < 4; ++p) {
            int idx = p * 256 + tid;
            int r = idx >> 3;
            int kc = (idx & 7) << 2;
            float4 v = make_float4(0.f, 0.f, 0.f, 0.f);
            if (r < rows) v = *(const float4*)(Xb + (size_t)r * IN_F + k0 + kc);
            s16x4 b;
            b.x = f2bf(v.x); b.y = f2bf(v.y); b.z = f2bf(v.z); b.w = f2bf(v.w);
            *(s16x4*)&As[r][kc] = b;
        }
        #pragma unroll
        for (int p = 0; p < 4; ++p) {
            int idx = p * 256 + tid;
            int r = idx >> 3;
            int kc = (idx & 7) << 2;
            float4 v = *(const float4*)(Wb + (size_t)r * IN_F + k0 + kc);
            s16x4 b;
            b.x = f2bf(v.x); b.y = f2bf(v.y); b.z = f2bf(v.z); b.w = f2bf(v.w);
            *(s16x4*)&Bs[r][kc] = b;
        }
        __syncthreads();

        s16x8 af[4], bf[4];
        #pragma unroll
        for (int i = 0; i < 4; ++i)
            af[i] = *(const s16x8*)&As[wm + i * 16 + lrow][kg * 8];
        #pragma unroll
        for (int j = 0; j < 4; ++j)
            bf[j] = *(const s16x8*)&Bs[wn + j * 16 + lrow][kg * 8];

        #pragma unroll
        for (int i = 0; i < 4; ++i)
            #pragma unroll
            for (int j = 0; j < 4; ++j)
                acc[i][j] = __builtin_amdgcn_mfma_f32_16x16x32_bf16(
                    af[i], bf[j], acc[i][j], 0, 0, 0);
    }

    float bv[4];
    #pragma unroll
    for (int j = 0; j < 4; ++j)
        bv[j] = Bias[(size_t)e_found * OUT_F + n0 + wn + j * 16 + lrow];

    #pragma unroll
    for (int i = 0; i < 4; ++i) {
        #pragma unroll
        for (int r = 0; r < 4; ++r) {
            int rr = wm + i * 16 + kg * 4 + r;
            if (rr < rows) {
                float* yrow = Y + (size_t)(row0 + rr) * OUT_F + n0;
                #pragma unroll
                for (int j = 0; j < 4; ++j)
                    yrow[wn + j * 16 + lrow] = acc[i][j][r] + bv[j];
            }
        }
    }
}

extern "C" void kernel_launch(void* const* d_in, const int* in_sizes, int n_in,
                              void* d_out, int out_size, void* d_ws, size_t ws_size,
                              hipStream_t stream) {
    const float* X = (const float*)d_in[0];
    const void* off = d_in[1];
    const float* W = (const float*)d_in[2];
    const float* Bias = (const float*)d_in[3];
    float* Y = (float*)d_out;

    const int NEXP1 = in_sizes[1];
    const int NEXP = NEXP1 - 1;
    const int OUT_F = in_sizes[3] / NEXP;
    const int IN_F = (int)((long long)in_sizes[2] / NEXP / OUT_F);
    const int T = in_sizes[0] / IN_F;

    const long long Xn = (long long)T * IN_F;                    // elements
    const long long Wn = (long long)NEXP * OUT_F * IN_F;
    const size_t need = (size_t)(Xn + Wn) * sizeof(short);

    const bool shape_ok = (OUT_F % QBN == 0) && (IN_F % QBK == 0) && (IN_F >= 3 * QBK) &&
                          (Xn % 4 == 0) && (Wn % 4 == 0);

    if (shape_ok && ws_size >= need) {
        short* wsX = (short*)d_ws;
        short* wsW = wsX + Xn;
        {
            long long n4 = Xn / 4;
            int blks = (int)((n4 + 255) / 256); if (blks > 4096) blks = 4096;
            cvt_kernel<<<blks, 256, 0, stream>>>(X, wsX, n4);
        }
        {
            long long n4 = Wn / 4;
            int blks = (int)((n4 + 255) / 256); if (blks > 4096) blks = 4096;
            cvt_kernel<<<blks, 256, 0, stream>>>(W, wsW, n4);
        }
        const int maxRowTiles = T / QBM + NEXP;
        dim3 grid(OUT_F / QBN, maxRowTiles);
        moe_gemm_bf16_256<<<grid, QTHREADS, 0, stream>>>(wsX, off, wsW, Bias, Y,
                                                         IN_F, OUT_F, NEXP, T);
    } else {
        const int maxRowTiles = T / FBM + NEXP;
        dim3 grid(OUT_F / FBN, maxRowTiles);
        moe_gemm_f32<<<grid, 256, 0, stream>>>(X, off, W, Bias, Y,
                                               IN_F, OUT_F, NEXP, T);
    }
}

// Round 3
// 529.523 us; speedup vs baseline: 1.1580x; 1.0816x over previous
//
#include <hip/hip_runtime.h>

// MoE grouped GEMM: Y[T, OUT] = X[T, IN] @ W[e, OUT, IN]^T + bias[e, OUT]
//
// Round 6: REVERT to the multi-block-per-CU m97 structure (session-0 kernel,
// 505 us) after two pipelined rewrites regressed (r4 416 TF, r5 490 TF vs
// ~620 TF for the original). Diagnosis: 1 block/CU + barrier-per-tile means
// any memory stall freezes the CU; 128^2/BK=32/16KB-LDS gives ~5 blocks/CU
// and implicit wave-level overlap (m114) that beats explicit counted-vmcnt
// pipelines at this occupancy. Kept from r4/r5 (verified twice, 0 bank
// conflicts): XOR swizzle via pre-swizzled global source + swizzled ds_read;
// row-clamp for partial expert tiles. New:
//   - m204 bijective XCD-chunked block remap: each XCD owns 2 W n-panels for
//     all row-tiles (W stays L2-resident; X streams once per XCD, y-ordered)
//   - cvt kernels: 32B-load/16B-store grid-stride, 2048 blocks (to rule the
//     ~290 us non-GEMM residual in or out as cvt cost)

typedef __attribute__((ext_vector_type(8))) short s16x8;   // 8 bf16
typedef __attribute__((ext_vector_type(4))) short s16x4;   // 4 bf16
typedef __attribute__((ext_vector_type(4))) float f32x4;

typedef __attribute__((address_space(1))) void gv_t;       // global
typedef __attribute__((address_space(3))) void lv_t;       // LDS

// main kernel geometry (m97 structure)
#define BM 128
#define BN 128
#define BK 32

// fallback kernel geometry
#define FBM 128
#define FBN 128
#define FBK 32
#define LDK 40

__device__ __forceinline__ short f2bf(float f) {
    union { float f; unsigned u; } v; v.f = f;
    unsigned r = v.u + 0x7FFFu + ((v.u >> 16) & 1u);
    return (short)(r >> 16);
}

__device__ __forceinline__ long long load_off(const void* p, int i, bool i64) {
    if (i64) return ((const long long*)p)[i];
    return (long long)((const int*)p)[i];
}

// ---- fp32 -> bf16 convert: 32 B load / 16 B store per thread-iter ----
__global__ __launch_bounds__(256)
void cvt_kernel(const float* __restrict__ src, short* __restrict__ dst, long long n8) {
    long long stride = (long long)gridDim.x * 256;
    for (long long i = (long long)blockIdx.x * 256 + threadIdx.x; i < n8; i += stride) {
        float4 a = ((const float4*)src)[2 * i];
        float4 b = ((const float4*)src)[2 * i + 1];
        s16x8 o;
        o[0] = f2bf(a.x); o[1] = f2bf(a.y); o[2] = f2bf(a.z); o[3] = f2bf(a.w);
        o[4] = f2bf(b.x); o[5] = f2bf(b.y); o[6] = f2bf(b.z); o[7] = f2bf(b.w);
        ((s16x8*)dst)[i] = o;
    }
}

// ---- map row-tile slot -> (expert, row0, rows) for tile height bm ----
__device__ __forceinline__ bool sched_tile(const void* offp, bool off_i64, int NEXP,
                                           int slot, int bm,
                                           int& e_out, long long& row0, int& rows) {
    int acc_t = 0;
    for (int e = 0; e < NEXP; ++e) {
        long long s = load_off(offp, e, off_i64);
        long long t = load_off(offp, e + 1, off_i64);
        int n = (int)(t - s);
        int nt = (n + bm - 1) / bm;
        if (slot < acc_t + nt) {
            int lt = slot - acc_t;
            row0 = s + (long long)lt * bm;
            rows = (int)(t - row0);
            if (rows > bm) rows = bm;
            e_out = e;
            return true;
        }
        acc_t += nt;
    }
    return false;
}

// ---- main GEMM: 128x128 tile, BK=32, 2-sync per K-step, ~5 blocks/CU ----
__global__ __launch_bounds__(256)
void moe_gemm_bf16(const short* __restrict__ Xb16,
                   const void* __restrict__ offp,
                   const short* __restrict__ Wb16,
                   const float* __restrict__ Bias,
                   float* __restrict__ Y,
                   int IN_F, int OUT_F, int NEXP, int Ttot) {
    const bool off_i64 = (((const int*)offp)[NEXP] != Ttot);

    // m204 bijective XCD-chunked remap: hw flat id -> work id such that
    // XCD q (= hw%8) gets a contiguous work chunk; decompose work with the
    // row-tile index fastest so each XCD sweeps all row-tiles of its 2
    // n-panels in order (W L2-resident; X streamed once, temporally local).
    const int gx = gridDim.x, gy = gridDim.y;
    const int nwg = gx * gy;
    const int hw = blockIdx.x + gx * blockIdx.y;
    const int q = nwg >> 3, r = nwg & 7;
    const int xcd = hw & 7, lid = hw >> 3;
    const int work = (xcd < r ? xcd * (q + 1) : r * (q + 1) + (xcd - r) * q) + lid;
    const int wx = work / gy;          // n-block
    const int wy = work % gy;          // row-tile slot

    int e_found; long long row0; int rows;
    if (!sched_tile(offp, off_i64, NEXP, wy, BM, e_found, row0, rows)) return;

    const int n0 = wx * BN;
    const int tid = threadIdx.x;
    const int wave = tid >> 6;          // 0..3
    const int lane = tid & 63;
    const int wm = (wave & 1) * 64;
    const int wn = (wave >> 1) * 64;
    const int lrow = lane & 15;
    const int kg = lane >> 4;           // 0..3
    const int swr = (lrow >> 1) & 3;    // read-side swizzle key

    // unpadded row-major [row][32] (64 B rows), single-buffered.
    // Swizzle contract (verified r4/r5, 0 conflicts): physical granule
    // (row, g) holds logical granule g ^ ((row>>1)&3); write side permutes
    // the GLOBAL source column, read side XORs the granule index.
    __shared__ __align__(16) short As[BM * BK];   // 8 KB
    __shared__ __align__(16) short Bs[BN * BK];   // 8 KB

    const short* Xb = Xb16 + (size_t)row0 * IN_F;
    const short* Wb = Wb16 + (size_t)e_found * OUT_F * IN_F + (size_t)n0 * IN_F;

    // staging: one global_load_lds = 1 KB = 16 rows x 64 B;
    // lane l -> row l>>2, granule l&3; LDS dest = uniform base + lane*16.
    const int lr4 = lane >> 2;                               // 0..15
    const int colOff = ((lane & 3) ^ ((lr4 >> 1) & 3)) * 8;  // inv-swz src col (shorts)
    const int rbase = wave * 16 + lr4;                       // 0..63
    const int ra0 = rbase;                                   // A rows 0..63
    const int ra1 = 64 + rbase;                              // A rows 64..127
    const int ra0c = ra0 < rows ? ra0 : rows - 1;            // clamp: garbage rows
    const int ra1c = ra1 < rows ? ra1 : rows - 1;            // are never stored

    const short* srcA0 = Xb + (size_t)ra0c * IN_F + colOff;
    const short* srcA1 = Xb + (size_t)ra1c * IN_F + colOff;
    const short* srcB0 = Wb + (size_t)rbase * IN_F + colOff;
    const short* srcB1 = Wb + (size_t)(64 + rbase) * IN_F + colOff;
    const int dA0 = wave * 512;          // shorts; wave-uniform LDS bases
    const int dA1 = 2048 + wave * 512;
    const int dB0 = wave * 512;
    const int dB1 = 2048 + wave * 512;

    f32x4 acc[4][4] = {};

    for (int k0 = 0; k0 < IN_F; k0 += BK) {
        __syncthreads();   // protect LDS from previous iteration's readers
        __builtin_amdgcn_global_load_lds((gv_t*)(srcA0 + k0), (lv_t*)(As + dA0), 16, 0, 0);
        __builtin_amdgcn_global_load_lds((gv_t*)(srcA1 + k0), (lv_t*)(As + dA1), 16, 0, 0);
        __builtin_amdgcn_global_load_lds((gv_t*)(srcB0 + k0), (lv_t*)(Bs + dB0), 16, 0, 0);
        __builtin_amdgcn_global_load_lds((gv_t*)(srcB1 + k0), (lv_t*)(Bs + dB1), 16, 0, 0);
        __syncthreads();   // drain (compiler inserts vmcnt(0) before barrier)

        s16x8 af[4], bf[4];
        #pragma unroll
        for (int i = 0; i < 4; ++i)
            af[i] = *(const s16x8*)&As[(wm + i * 16 + lrow) * BK + ((kg ^ swr) * 8)];
        #pragma unroll
        for (int j = 0; j < 4; ++j)
            bf[j] = *(const s16x8*)&Bs[(wn + j * 16 + lrow) * BK + ((kg ^ swr) * 8)];

        #pragma unroll
        for (int i = 0; i < 4; ++i)
            #pragma unroll
            for (int j = 0; j < 4; ++j)
                acc[i][j] = __builtin_amdgcn_mfma_f32_16x16x32_bf16(
                    af[i], bf[j], acc[i][j], 0, 0, 0);
    }

    // epilogue: C/D map col = lane&15, row = (lane>>4)*4 + reg
    float bv[4];
    #pragma unroll
    for (int j = 0; j < 4; ++j)
        bv[j] = Bias[(size_t)e_found * OUT_F + n0 + wn + j * 16 + lrow];

    #pragma unroll
    for (int i = 0; i < 4; ++i) {
        #pragma unroll
        for (int r2 = 0; r2 < 4; ++r2) {
            int rr = wm + i * 16 + kg * 4 + r2;
            if (rr < rows) {
                float* yrow = Y + (size_t)(row0 + rr) * OUT_F + n0;
                #pragma unroll
                for (int j = 0; j < 4; ++j)
                    yrow[wn + j * 16 + lrow] = acc[i][j][r2] + bv[j];
            }
        }
    }
}

// ---- fallback: fp32 inputs, in-kernel cvt (round-2 kernel, verified) ----
__global__ __launch_bounds__(256, 2)
void moe_gemm_f32(const float* __restrict__ X,
                  const void* __restrict__ offp,
                  const float* __restrict__ W,
                  const float* __restrict__ Bias,
                  float* __restrict__ Y,
                  int IN_F, int OUT_F, int NEXP, int Ttot) {
    const bool off_i64 = (((const int*)offp)[NEXP] != Ttot);
    int e_found; long long row0; int rows;
    if (!sched_tile(offp, off_i64, NEXP, blockIdx.y, FBM, e_found, row0, rows)) return;

    const int n0 = blockIdx.x * FBN;
    const int tid = threadIdx.x;
    const int wave = tid >> 6;
    const int lane = tid & 63;
    const int wm = (wave & 1) * 64;
    const int wn = (wave >> 1) * 64;
    const int lrow = lane & 15;
    const int kg = lane >> 4;

    __shared__ __align__(16) short As[FBM][LDK];
    __shared__ __align__(16) short Bs[FBN][LDK];

    const float* Xb = X + (size_t)row0 * IN_F;
    const float* Wb = W + (size_t)e_found * OUT_F * IN_F + (size_t)n0 * IN_F;

    f32x4 acc[4][4] = {};

    for (int k0 = 0; k0 < IN_F; k0 += FBK) {
        __syncthreads();
        #pragma unroll
        for (int p = 0; p < 4; ++p) {
            int idx = p * 256 + tid;
            int r = idx >> 3;
            int kc = (idx & 7) << 2;
            float4 v = make_float4(0.f, 0.f, 0.f, 0.f);
            if (r < rows) v = *(const float4*)(Xb + (size_t)r * IN_F + k0 + kc);
            s16x4 b;
            b.x = f2bf(v.x); b.y = f2bf(v.y); b.z = f2bf(v.z); b.w = f2bf(v.w);
            *(s16x4*)&As[r][kc] = b;
        }
        #pragma unroll
        for (int p = 0; p < 4; ++p) {
            int idx = p * 256 + tid;
            int r = idx >> 3;
            int kc = (idx & 7) << 2;
            float4 v = *(const float4*)(Wb + (size_t)r * IN_F + k0 + kc);
            s16x4 b;
            b.x = f2bf(v.x); b.y = f2bf(v.y); b.z = f2bf(v.z); b.w = f2bf(v.w);
            *(s16x4*)&Bs[r][kc] = b;
        }
        __syncthreads();

        s16x8 af[4], bf[4];
        #pragma unroll
        for (int i = 0; i < 4; ++i)
            af[i] = *(const s16x8*)&As[wm + i * 16 + lrow][kg * 8];
        #pragma unroll
        for (int j = 0; j < 4; ++j)
            bf[j] = *(const s16x8*)&Bs[wn + j * 16 + lrow][kg * 8];

        #pragma unroll
        for (int i = 0; i < 4; ++i)
            #pragma unroll
            for (int j = 0; j < 4; ++j)
                acc[i][j] = __builtin_amdgcn_mfma_f32_16x16x32_bf16(
                    af[i], bf[j], acc[i][j], 0, 0, 0);
    }

    float bv[4];
    #pragma unroll
    for (int j = 0; j < 4; ++j)
        bv[j] = Bias[(size_t)e_found * OUT_F + n0 + wn + j * 16 + lrow];

    #pragma unroll
    for (int i = 0; i < 4; ++i) {
        #pragma unroll
        for (int r2 = 0; r2 < 4; ++r2) {
            int rr = wm + i * 16 + kg * 4 + r2;
            if (rr < rows) {
                float* yrow = Y + (size_t)(row0 + rr) * OUT_F + n0;
                #pragma unroll
                for (int j = 0; j < 4; ++j)
                    yrow[wn + j * 16 + lrow] = acc[i][j][r2] + bv[j];
            }
        }
    }
}

extern "C" void kernel_launch(void* const* d_in, const int* in_sizes, int n_in,
                              void* d_out, int out_size, void* d_ws, size_t ws_size,
                              hipStream_t stream) {
    const float* X = (const float*)d_in[0];
    const void* off = d_in[1];
    const float* W = (const float*)d_in[2];
    const float* Bias = (const float*)d_in[3];
    float* Y = (float*)d_out;

    const int NEXP1 = in_sizes[1];
    const int NEXP = NEXP1 - 1;
    const int OUT_F = in_sizes[3] / NEXP;
    const int IN_F = (int)((long long)in_sizes[2] / NEXP / OUT_F);
    const int T = in_sizes[0] / IN_F;

    const long long Xn = (long long)T * IN_F;                    // elements
    const long long Wn = (long long)NEXP * OUT_F * IN_F;
    const size_t need = (size_t)(Xn + Wn) * sizeof(short);

    const bool shape_ok = (OUT_F % BN == 0) && (IN_F % BK == 0) &&
                          (Xn % 8 == 0) && (Wn % 8 == 0);

    if (shape_ok && ws_size >= need) {
        short* wsX = (short*)d_ws;
        short* wsW = wsX + Xn;
        {
            long long n8 = Xn / 8;
            int blks = (int)((n8 + 255) / 256); if (blks > 2048) blks = 2048;
            cvt_kernel<<<blks, 256, 0, stream>>>(X, wsX, n8);
        }
        {
            long long n8 = Wn / 8;
            int blks = (int)((n8 + 255) / 256); if (blks > 2048) blks = 2048;
            cvt_kernel<<<blks, 256, 0, stream>>>(W, wsW, n8);
        }
        const int maxRowTiles = T / BM + NEXP;
        dim3 grid(OUT_F / BN, maxRowTiles);
        moe_gemm_bf16<<<grid, 256, 0, stream>>>(wsX, off, wsW, Bias, Y,
                                                IN_F, OUT_F, NEXP, T);
    } else {
        const int maxRowTiles = T / FBM + NEXP;
        dim3 grid(OUT_F / FBN, maxRowTiles);
        moe_gemm_f32<<<grid, 256, 0, stream>>>(X, off, W, Bias, Y,
                                               IN_F, OUT_F, NEXP, T);
    }
}

// Round 4
// 523.216 us; speedup vs baseline: 1.1720x; 1.0121x over previous
//
#include <hip/hip_runtime.h>

// MoE grouped GEMM: Y[T, OUT] = X[T, IN] @ W[e, OUT, IN]^T + bias[e, OUT]
//
// Round 7: keep r6's verified 128x128/BK=32 multi-block structure (572 TF) and
// remove its exposed staging latency: r6 did {barrier; STAGE; drain; compute}
// so every K-tile paid full L2/L3 load latency with only ~3 blocks/CU of
// cover. Now: T3 "minimum 2-phase" pipeline, deepened to 3 LDS slots (48 KB
// is free - occupancy is register-capped at 3 blocks/CU, LDS cap was 10):
//   iter t: STAGE(t+2) -> compute t -> s_waitcnt vmcnt(4) -> s_barrier
// Counted vmcnt (T4): tile t+2's 4 loads stay in flight across the barrier;
// never drain to 0 in the main loop. Race invariants:
//   - STAGE(t+2) writes slot (t-1)%3, whose readers (iter t-1 compute)
//     finished before iter t-1's end barrier  -> safe
//   - vmcnt(4)+barrier at iter t end: tile t+1 (issued iter t-1) resident
//     and visible before iter t+1 reads it    -> safe
//   - row-clamp keeps load counts uniform across waves -> vmcnt exact
// Unchanged from r6 (one-variable discipline): XOR swizzle (0 conflicts
// measured), XCD-chunked remap, epilogue, cvt kernels, f32 fallback.

typedef __attribute__((ext_vector_type(8))) short s16x8;   // 8 bf16
typedef __attribute__((ext_vector_type(4))) short s16x4;   // 4 bf16
typedef __attribute__((ext_vector_type(4))) float f32x4;

typedef __attribute__((address_space(1))) void gv_t;       // global
typedef __attribute__((address_space(3))) void lv_t;       // LDS

// main kernel geometry (m97 structure + 3-slot pipeline)
#define BM 128
#define BN 128
#define BK 32
#define SLOT (BM * BK)      // shorts per A (or B) slot: 4096 = 8 KB

// fallback kernel geometry
#define FBM 128
#define FBN 128
#define FBK 32
#define LDK 40

__device__ __forceinline__ short f2bf(float f) {
    union { float f; unsigned u; } v; v.f = f;
    unsigned r = v.u + 0x7FFFu + ((v.u >> 16) & 1u);
    return (short)(r >> 16);
}

__device__ __forceinline__ long long load_off(const void* p, int i, bool i64) {
    if (i64) return ((const long long*)p)[i];
    return (long long)((const int*)p)[i];
}

// ---- fp32 -> bf16 convert: 32 B load / 16 B store per thread-iter ----
__global__ __launch_bounds__(256)
void cvt_kernel(const float* __restrict__ src, short* __restrict__ dst, long long n8) {
    long long stride = (long long)gridDim.x * 256;
    for (long long i = (long long)blockIdx.x * 256 + threadIdx.x; i < n8; i += stride) {
        float4 a = ((const float4*)src)[2 * i];
        float4 b = ((const float4*)src)[2 * i + 1];
        s16x8 o;
        o[0] = f2bf(a.x); o[1] = f2bf(a.y); o[2] = f2bf(a.z); o[3] = f2bf(a.w);
        o[4] = f2bf(b.x); o[5] = f2bf(b.y); o[6] = f2bf(b.z); o[7] = f2bf(b.w);
        ((s16x8*)dst)[i] = o;
    }
}

// ---- map row-tile slot -> (expert, row0, rows) for tile height bm ----
__device__ __forceinline__ bool sched_tile(const void* offp, bool off_i64, int NEXP,
                                           int slot, int bm,
                                           int& e_out, long long& row0, int& rows) {
    int acc_t = 0;
    for (int e = 0; e < NEXP; ++e) {
        long long s = load_off(offp, e, off_i64);
        long long t = load_off(offp, e + 1, off_i64);
        int n = (int)(t - s);
        int nt = (n + bm - 1) / bm;
        if (slot < acc_t + nt) {
            int lt = slot - acc_t;
            row0 = s + (long long)lt * bm;
            rows = (int)(t - row0);
            if (rows > bm) rows = bm;
            e_out = e;
            return true;
        }
        acc_t += nt;
    }
    return false;
}

// ---- main GEMM: 128x128, BK=32, 3-slot pipeline, counted vmcnt ----
__global__ __launch_bounds__(256)
void moe_gemm_bf16(const short* __restrict__ Xb16,
                   const void* __restrict__ offp,
                   const short* __restrict__ Wb16,
                   const float* __restrict__ Bias,
                   float* __restrict__ Y,
                   int IN_F, int OUT_F, int NEXP, int Ttot) {
    const bool off_i64 = (((const int*)offp)[NEXP] != Ttot);

    // m204 bijective XCD-chunked remap (unchanged from r6)
    const int gx = gridDim.x, gy = gridDim.y;
    const int nwg = gx * gy;
    const int hw = blockIdx.x + gx * blockIdx.y;
    const int q = nwg >> 3, r = nwg & 7;
    const int xcd = hw & 7, lid = hw >> 3;
    const int work = (xcd < r ? xcd * (q + 1) : r * (q + 1) + (xcd - r) * q) + lid;
    const int wx = work / gy;          // n-block
    const int wy = work % gy;          // row-tile slot

    int e_found; long long row0; int rows;
    if (!sched_tile(offp, off_i64, NEXP, wy, BM, e_found, row0, rows)) return;

    const int n0 = wx * BN;
    const int tid = threadIdx.x;
    const int wave = tid >> 6;          // 0..3
    const int lane = tid & 63;
    const int wm = (wave & 1) * 64;
    const int wn = (wave >> 1) * 64;
    const int lrow = lane & 15;
    const int kg = lane >> 4;           // 0..3
    const int swr = (lrow >> 1) & 3;    // read-side swizzle key

    // 3 rotating slots per operand, unpadded row-major [row][32] (64 B rows).
    // Swizzle (verified r4-r6, 0 conflicts): physical granule (row,g) holds
    // logical granule g ^ ((row>>1)&3); write side permutes the GLOBAL source
    // column, read side XORs the granule index.
    __shared__ __align__(16) short As[3 * SLOT];   // 24 KB
    __shared__ __align__(16) short Bs[3 * SLOT];   // 24 KB

    const short* Xb = Xb16 + (size_t)row0 * IN_F;
    const short* Wb = Wb16 + (size_t)e_found * OUT_F * IN_F + (size_t)n0 * IN_F;

    // staging: one global_load_lds = 1 KB = 16 rows x 64 B;
    // lane l -> row l>>2, granule l&3; LDS dest = uniform base + lane*16.
    const int lr4 = lane >> 2;                               // 0..15
    const int colOff = ((lane & 3) ^ ((lr4 >> 1) & 3)) * 8;  // inv-swz src col (shorts)
    const int rbase = wave * 16 + lr4;                       // 0..63
    const int ra0 = rbase;                                   // A rows 0..63
    const int ra1 = 64 + rbase;                              // A rows 64..127
    const int ra0c = ra0 < rows ? ra0 : rows - 1;            // clamp: garbage rows
    const int ra1c = ra1 < rows ? ra1 : rows - 1;            // are never stored

    const short* srcA0 = Xb + (size_t)ra0c * IN_F + colOff;
    const short* srcA1 = Xb + (size_t)ra1c * IN_F + colOff;
    const short* srcB0 = Wb + (size_t)rbase * IN_F + colOff;
    const short* srcB1 = Wb + (size_t)(64 + rbase) * IN_F + colOff;
    const int dA0 = wave * 512;          // shorts; wave-uniform LDS bases
    const int dA1 = 2048 + wave * 512;
    const int dB0 = wave * 512;
    const int dB1 = 2048 + wave * 512;

    const int nkt = IN_F / BK;

    // 4 loads per STAGE, uniform across waves (vmcnt arithmetic depends on it)
    auto STAGE = [&](int kt_, int slot_) {
        const int k0_ = kt_ * BK;
        __builtin_amdgcn_global_load_lds((gv_t*)(srcA0 + k0_),
                                         (lv_t*)(As + slot_ * SLOT + dA0), 16, 0, 0);
        __builtin_amdgcn_global_load_lds((gv_t*)(srcA1 + k0_),
                                         (lv_t*)(As + slot_ * SLOT + dA1), 16, 0, 0);
        __builtin_amdgcn_global_load_lds((gv_t*)(srcB0 + k0_),
                                         (lv_t*)(Bs + slot_ * SLOT + dB0), 16, 0, 0);
        __builtin_amdgcn_global_load_lds((gv_t*)(srcB1 + k0_),
                                         (lv_t*)(Bs + slot_ * SLOT + dB1), 16, 0, 0);
    };

    // prologue: tiles 0,1 in flight; wait tile 0, keep tile 1 flying
    STAGE(0, 0);
    if (nkt > 1) {
        STAGE(1, 1);
        asm volatile("s_waitcnt vmcnt(4)" ::: "memory");
    } else {
        asm volatile("s_waitcnt vmcnt(0)" ::: "memory");
    }
    asm volatile("s_barrier" ::: "memory");

    f32x4 acc[4][4] = {};

    int sc = 0;                           // slot holding tile kt
    for (int kt = 0; kt < nkt; ++kt) {
        // stage tile kt+2 into slot (kt+2)%3 = (kt-1)%3 (freed by the
        // barrier that ended iteration kt-1)
        if (kt + 2 < nkt) {
            const int sp = (sc >= 1) ? sc - 1 : 2;   // (sc+2)%3
            STAGE(kt + 2, sp);
        }

        const short* aS = As + sc * SLOT;
        const short* bS = Bs + sc * SLOT;
        s16x8 af[4], bf[4];
        #pragma unroll
        for (int i = 0; i < 4; ++i)
            af[i] = *(const s16x8*)&aS[(wm + i * 16 + lrow) * BK + ((kg ^ swr) * 8)];
        #pragma unroll
        for (int j = 0; j < 4; ++j)
            bf[j] = *(const s16x8*)&bS[(wn + j * 16 + lrow) * BK + ((kg ^ swr) * 8)];

        #pragma unroll
        for (int i = 0; i < 4; ++i)
            #pragma unroll
            for (int j = 0; j < 4; ++j)
                acc[i][j] = __builtin_amdgcn_mfma_f32_16x16x32_bf16(
                    af[i], bf[j], acc[i][j], 0, 0, 0);

        // end of iter: ensure tile kt+1 resident for everyone; keep kt+2's
        // 4 loads in flight (counted vmcnt, never 0 mid-loop)
        if (kt + 1 < nkt) {
            if (kt + 2 < nkt) asm volatile("s_waitcnt vmcnt(4)" ::: "memory");
            else              asm volatile("s_waitcnt vmcnt(0)" ::: "memory");
            asm volatile("s_barrier" ::: "memory");
        }
        sc = (sc >= 2) ? 0 : sc + 1;
    }

    // epilogue: C/D map col = lane&15, row = (lane>>4)*4 + reg
    float bv[4];
    #pragma unroll
    for (int j = 0; j < 4; ++j)
        bv[j] = Bias[(size_t)e_found * OUT_F + n0 + wn + j * 16 + lrow];

    #pragma unroll
    for (int i = 0; i < 4; ++i) {
        #pragma unroll
        for (int r2 = 0; r2 < 4; ++r2) {
            int rr = wm + i * 16 + kg * 4 + r2;
            if (rr < rows) {
                float* yrow = Y + (size_t)(row0 + rr) * OUT_F + n0;
                #pragma unroll
                for (int j = 0; j < 4; ++j)
                    yrow[wn + j * 16 + lrow] = acc[i][j][r2] + bv[j];
            }
        }
    }
}

// ---- fallback: fp32 inputs, in-kernel cvt (round-2 kernel, verified) ----
__global__ __launch_bounds__(256, 2)
void moe_gemm_f32(const float* __restrict__ X,
                  const void* __restrict__ offp,
                  const float* __restrict__ W,
                  const float* __restrict__ Bias,
                  float* __restrict__ Y,
                  int IN_F, int OUT_F, int NEXP, int Ttot) {
    const bool off_i64 = (((const int*)offp)[NEXP] != Ttot);
    int e_found; long long row0; int rows;
    if (!sched_tile(offp, off_i64, NEXP, blockIdx.y, FBM, e_found, row0, rows)) return;

    const int n0 = blockIdx.x * FBN;
    const int tid = threadIdx.x;
    const int wave = tid >> 6;
    const int lane = tid & 63;
    const int wm = (wave & 1) * 64;
    const int wn = (wave >> 1) * 64;
    const int lrow = lane & 15;
    const int kg = lane >> 4;

    __shared__ __align__(16) short As[FBM][LDK];
    __shared__ __align__(16) short Bs[FBN][LDK];

    const float* Xb = X + (size_t)row0 * IN_F;
    const float* Wb = W + (size_t)e_found * OUT_F * IN_F + (size_t)n0 * IN_F;

    f32x4 acc[4][4] = {};

    for (int k0 = 0; k0 < IN_F; k0 += FBK) {
        __syncthreads();
        #pragma unroll
        for (int p = 0; p < 4; ++p) {
            int idx = p * 256 + tid;
            int r = idx >> 3;
            int kc = (idx & 7) << 2;
            float4 v = make_float4(0.f, 0.f, 0.f, 0.f);
            if (r < rows) v = *(const float4*)(Xb + (size_t)r * IN_F + k0 + kc);
            s16x4 b;
            b.x = f2bf(v.x); b.y = f2bf(v.y); b.z = f2bf(v.z); b.w = f2bf(v.w);
            *(s16x4*)&As[r][kc] = b;
        }
        #pragma unroll
        for (int p = 0; p < 4; ++p) {
            int idx = p * 256 + tid;
            int r = idx >> 3;
            int kc = (idx & 7) << 2;
            float4 v = *(const float4*)(Wb + (size_t)r * IN_F + k0 + kc);
            s16x4 b;
            b.x = f2bf(v.x); b.y = f2bf(v.y); b.z = f2bf(v.z); b.w = f2bf(v.w);
            *(s16x4*)&Bs[r][kc] = b;
        }
        __syncthreads();

        s16x8 af[4], bf[4];
        #pragma unroll
        for (int i = 0; i < 4; ++i)
            af[i] = *(const s16x8*)&As[wm + i * 16 + lrow][kg * 8];
        #pragma unroll
        for (int j = 0; j < 4; ++j)
            bf[j] = *(const s16x8*)&Bs[wn + j * 16 + lrow][kg * 8];

        #pragma unroll
        for (int i = 0; i < 4; ++i)
            #pragma unroll
            for (int j = 0; j < 4; ++j)
                acc[i][j] = __builtin_amdgcn_mfma_f32_16x16x32_bf16(
                    af[i], bf[j], acc[i][j], 0, 0, 0);
    }

    float bv[4];
    #pragma unroll
    for (int j = 0; j < 4; ++j)
        bv[j] = Bias[(size_t)e_found * OUT_F + n0 + wn + j * 16 + lrow];

    #pragma unroll
    for (int i = 0; i < 4; ++i) {
        #pragma unroll
        for (int r2 = 0; r2 < 4; ++r2) {
            int rr = wm + i * 16 + kg * 4 + r2;
            if (rr < rows) {
                float* yrow = Y + (size_t)(row0 + rr) * OUT_F + n0;
                #pragma unroll
                for (int j = 0; j < 4; ++j)
                    yrow[wn + j * 16 + lrow] = acc[i][j][r2] + bv[j];
            }
        }
    }
}

extern "C" void kernel_launch(void* const* d_in, const int* in_sizes, int n_in,
                              void* d_out, int out_size, void* d_ws, size_t ws_size,
                              hipStream_t stream) {
    const float* X = (const float*)d_in[0];
    const void* off = d_in[1];
    const float* W = (const float*)d_in[2];
    const float* Bias = (const float*)d_in[3];
    float* Y = (float*)d_out;

    const int NEXP1 = in_sizes[1];
    const int NEXP = NEXP1 - 1;
    const int OUT_F = in_sizes[3] / NEXP;
    const int IN_F = (int)((long long)in_sizes[2] / NEXP / OUT_F);
    const int T = in_sizes[0] / IN_F;

    const long long Xn = (long long)T * IN_F;                    // elements
    const long long Wn = (long long)NEXP * OUT_F * IN_F;
    const size_t need = (size_t)(Xn + Wn) * sizeof(short);

    const bool shape_ok = (OUT_F % BN == 0) && (IN_F % BK == 0) &&
                          (Xn % 8 == 0) && (Wn % 8 == 0);

    if (shape_ok && ws_size >= need) {
        short* wsX = (short*)d_ws;
        short* wsW = wsX + Xn;
        {
            long long n8 = Xn / 8;
            int blks = (int)((n8 + 255) / 256); if (blks > 2048) blks = 2048;
            cvt_kernel<<<blks, 256, 0, stream>>>(X, wsX, n8);
        }
        {
            long long n8 = Wn / 8;
            int blks = (int)((n8 + 255) / 256); if (blks > 2048) blks = 2048;
            cvt_kernel<<<blks, 256, 0, stream>>>(W, wsW, n8);
        }
        const int maxRowTiles = T / BM + NEXP;
        dim3 grid(OUT_F / BN, maxRowTiles);
        moe_gemm_bf16<<<grid, 256, 0, stream>>>(wsX, off, wsW, Bias, Y,
                                                IN_F, OUT_F, NEXP, T);
    } else {
        const int maxRowTiles = T / FBM + NEXP;
        dim3 grid(OUT_F / FBN, maxRowTiles);
        moe_gemm_f32<<<grid, 256, 0, stream>>>(X, off, W, Bias, Y,
                                               IN_F, OUT_F, NEXP, T);
    }
}